// Round 4
// baseline (201.102 us; speedup 1.0000x reference)
//
#include <hip/hip_runtime.h>
#include <math.h>

// Tiles: B*NTH*NTW = 64*56*56
constexpr int TT = 64 * 56 * 56;   // 200704
// M = 8 slots, DF = 8 flux dims, output row = 2 + 8 + 1 = 11 floats
// out per tile = 88 floats = 22 float4. TT*22 float4 = 17248 blocks of 256.

// Fused kernel: each block covers 256 consecutive out-float4s (<= 13 tiles).
// Phase 1: lanes 0..nt-1 of wave 0 compute per-tile matching -> LDS rowsrc
//          (4 bits per output row: (8|j) if matched from true row j).
//          Boundary tiles are recomputed by two blocks — deterministic.
// Phase 2: all 256 threads emit coalesced float4 stores, gathering matched
//          true locs/fluxes. Matched rows always have indicator 1.0
//          (one2one implies match2[k] < tn).
__global__ __launch_bounds__(256) void mvd_fused(
    const float4* __restrict__ el4,   // est_locs  [TT*4] float4
    const float4* __restrict__ tl4,   // true_locs [TT*4] float4
    const int*    __restrict__ en_,
    const int*    __restrict__ tn_,
    float4*       __restrict__ out4)  // [TT*22]
{
#pragma clang fp contract(off)
    const int base = blockIdx.x * 256;
    const int idx  = base + threadIdx.x;
    const int t0   = base / 22;
    const int t1   = (base + 255) / 22;
    const int nt   = t1 - t0 + 1;     // <= 13

    __shared__ int s_rowsrc[16];

    if ((int)threadIdx.x < nt) {
        const int t  = t0 + threadIdx.x;
        const int en = en_[t];
        const int tn = tn_[t];

        float4 ea = el4[t * 4 + 0], eb = el4[t * 4 + 1];
        float4 ec = el4[t * 4 + 2], ed = el4[t * 4 + 3];
        float4 ta = tl4[t * 4 + 0], tb = tl4[t * 4 + 1];
        float4 tc = tl4[t * 4 + 2], td = tl4[t * 4 + 3];

        float mex[8], mey[8], mtx[8], mty[8];
        {
            const float exs[8] = {ea.x, ea.z, eb.x, eb.z, ec.x, ec.z, ed.x, ed.z};
            const float eys[8] = {ea.y, ea.w, eb.y, eb.w, ec.y, ec.w, ed.y, ed.w};
            const float txs[8] = {ta.x, ta.z, tb.x, tb.z, tc.x, tc.z, td.x, td.z};
            const float tys[8] = {ta.y, ta.w, tb.y, tb.w, tc.y, tc.w, td.y, td.w};
#pragma unroll
            for (int i = 0; i < 8; i++) {
                mex[i] = (i < en) ? exs[i] : 100.0f;
                mey[i] = (i < en) ? eys[i] : 100.0f;
                mtx[i] = (i < tn) ? txs[i] : 100.0f;
                mty[i] = (i < tn) ? tys[i] : 100.0f;
            }
        }

        // sqrt REQUIRED: fp32 sqrt rounding can merge values distinct in
        // squared form; numpy argmin tie-breaks to the earlier index on the
        // rounded values. HIP sqrtf (no -ffast-math) is IEEE == np.sqrt.
        // Strict '<' + ascending index == numpy first-occurrence argmin.
        float colmin[8];
        int   m1[8], m2[8];
#pragma unroll
        for (int j = 0; j < 8; j++) { colmin[j] = 1e30f; m1[j] = 0; }
#pragma unroll
        for (int i = 0; i < 8; i++) {
            float rmin = 1e30f;
            int   rj = 0;
#pragma unroll
            for (int j = 0; j < 8; j++) {
                float dx = mex[i] - mtx[j];
                float dy = mey[i] - mty[j];
                float dx2 = dx * dx;
                float dy2 = dy * dy;
                float d = sqrtf(dx2 + dy2);
                if (d < rmin) { rmin = d; rj = j; }
                if (d < colmin[j]) { colmin[j] = d; m1[j] = i; }
            }
            m2[i] = rj;
        }

        int m1p = 0;
#pragma unroll
        for (int j = 0; j < 8; j++) m1p |= m1[j] << (3 * j);

        // one2one + scatter (ascending k, last-wins == numpy fancy assign)
        int rowsrc = 0;
#pragma unroll
        for (int k = 0; k < 8; k++) {
            int j = m2[k];
            int m1j = (m1p >> (3 * j)) & 7;
            bool o2o = (m1j == k) && (m1[k] < en) && (m2[k] < tn);
            if (o2o) {
                int r = m1[k];
                rowsrc = (rowsrc & ~(0xF << (4 * r))) | ((8 | j) << (4 * r));
            }
        }
        s_rowsrc[threadIdx.x] = rowsrc;
    }
    __syncthreads();

    // Phase 2: coalesced output
    const float* tl = (const float*)tl4;
    const int t = idx / 22;             // magic-mul
    const int q = idx - t * 22;
    const int w = s_rowsrc[t - t0];

    float res[4];
#pragma unroll
    for (int u = 0; u < 4; u++) {
        int p = 4 * q + u;              // 0..87 within tile
        int r = (p * 94) >> 10;         // == p/11 for p in [0,88)
        int c = p - r * 11;
        int v = (w >> (4 * r)) & 15;
        float val = 0.0f;
        if (v & 8) {
            int j = v & 7;
            if (c == 10)      val = 1.0f;
            else if (c < 2)   val = tl[(t << 4) + (j << 1) + c];
            else              val = __builtin_nontemporal_load(
                                        /*fluxes*/ ((const float*)nullptr == nullptr
                                        ? &((const float*)0)[0] : nullptr)), val = 0.0f;
        }
        res[u] = val;
    }
    // (see note below — flux path re-done without the botched NT load)
    out4[idx] = make_float4(res[0], res[1], res[2], res[3]);
}

extern "C" void kernel_launch(void* const*, const int*, int, void*, int, void*, size_t, hipStream_t);

// ---- clean implementation (the above experiment with nontemporal loads was
//      removed; this is the kernel actually launched) ----
__global__ __launch_bounds__(256) void mvd_fused2(
    const float4* __restrict__ el4,
    const float4* __restrict__ tl4,
    const float*  __restrict__ tf,    // true_fluxes [TT*64]
    const int*    __restrict__ en_,
    const int*    __restrict__ tn_,
    float4*       __restrict__ out4)
{
#pragma clang fp contract(off)
    const int base = blockIdx.x * 256;
    const int idx  = base + threadIdx.x;
    const int t0   = base / 22;
    const int t1   = (base + 255) / 22;
    const int nt   = t1 - t0 + 1;

    __shared__ int s_rowsrc[16];

    if ((int)threadIdx.x < nt) {
        const int t  = t0 + threadIdx.x;
        const int en = en_[t];
        const int tn = tn_[t];

        float4 ea = el4[t * 4 + 0], eb = el4[t * 4 + 1];
        float4 ec = el4[t * 4 + 2], ed = el4[t * 4 + 3];
        float4 ta = tl4[t * 4 + 0], tb = tl4[t * 4 + 1];
        float4 tc = tl4[t * 4 + 2], td = tl4[t * 4 + 3];

        float mex[8], mey[8], mtx[8], mty[8];
        {
            const float exs[8] = {ea.x, ea.z, eb.x, eb.z, ec.x, ec.z, ed.x, ed.z};
            const float eys[8] = {ea.y, ea.w, eb.y, eb.w, ec.y, ec.w, ed.y, ed.w};
            const float txs[8] = {ta.x, ta.z, tb.x, tb.z, tc.x, tc.z, td.x, td.z};
            const float tys[8] = {ta.y, ta.w, tb.y, tb.w, tc.y, tc.w, td.y, td.w};
#pragma unroll
            for (int i = 0; i < 8; i++) {
                mex[i] = (i < en) ? exs[i] : 100.0f;
                mey[i] = (i < en) ? eys[i] : 100.0f;
                mtx[i] = (i < tn) ? txs[i] : 100.0f;
                mty[i] = (i < tn) ? tys[i] : 100.0f;
            }
        }

        float colmin[8];
        int   m1[8], m2[8];
#pragma unroll
        for (int j = 0; j < 8; j++) { colmin[j] = 1e30f; m1[j] = 0; }
#pragma unroll
        for (int i = 0; i < 8; i++) {
            float rmin = 1e30f;
            int   rj = 0;
#pragma unroll
            for (int j = 0; j < 8; j++) {
                float dx = mex[i] - mtx[j];
                float dy = mey[i] - mty[j];
                float dx2 = dx * dx;
                float dy2 = dy * dy;
                float d = sqrtf(dx2 + dy2);
                if (d < rmin) { rmin = d; rj = j; }
                if (d < colmin[j]) { colmin[j] = d; m1[j] = i; }
            }
            m2[i] = rj;
        }

        int m1p = 0;
#pragma unroll
        for (int j = 0; j < 8; j++) m1p |= m1[j] << (3 * j);

        int rowsrc = 0;
#pragma unroll
        for (int k = 0; k < 8; k++) {
            int j = m2[k];
            int m1j = (m1p >> (3 * j)) & 7;
            bool o2o = (m1j == k) && (m1[k] < en) && (m2[k] < tn);
            if (o2o) {
                int r = m1[k];
                rowsrc = (rowsrc & ~(0xF << (4 * r))) | ((8 | j) << (4 * r));
            }
        }
        s_rowsrc[threadIdx.x] = rowsrc;
    }
    __syncthreads();

    const float* tl = (const float*)tl4;
    const int t = idx / 22;
    const int q = idx - t * 22;
    const int w = s_rowsrc[t - t0];

    float res[4];
#pragma unroll
    for (int u = 0; u < 4; u++) {
        int p = 4 * q + u;
        int r = (p * 94) >> 10;         // p/11 for p in [0,88)
        int c = p - r * 11;
        int v = (w >> (4 * r)) & 15;
        float val = 0.0f;
        if (v & 8) {
            int j = v & 7;
            if (c == 10)      val = 1.0f;
            else if (c < 2)   val = tl[(t << 4) + (j << 1) + c];
            else              val = tf[(t << 6) + (j << 3) + (c - 2)];
        }
        res[u] = val;
    }
    out4[idx] = make_float4(res[0], res[1], res[2], res[3]);
}

extern "C" void kernel_launch(void* const* d_in, const int* in_sizes, int n_in,
                              void* d_out, int out_size, void* d_ws, size_t ws_size,
                              hipStream_t stream) {
    const float* est_locs    = (const float*)d_in[0];
    const float* true_locs   = (const float*)d_in[1];
    const float* true_fluxes = (const float*)d_in[2];
    const int*   est_n       = (const int*)d_in[3];
    const int*   true_n      = (const int*)d_in[4];
    float* out = (float*)d_out;

    const int blocks = (TT * 22) / 256;   // 17248 exactly
    mvd_fused2<<<blocks, 256, 0, stream>>>(
        (const float4*)est_locs, (const float4*)true_locs, true_fluxes,
        est_n, true_n, (float4*)out);
}

// Round 5
// 151.322 us; speedup vs baseline: 1.3290x; 1.3290x over previous
//
#include <hip/hip_runtime.h>
#include <math.h>

// Tiles: B*NTH*NTW = 64*56*56
constexpr int TT = 64 * 56 * 56;   // 200704 == 784 * 256
// M = 8 slots, DF = 8 flux dims, output row = 2 + 8 + 1 = 11 floats
// out per tile = 88 floats = 22 float4.
//
// One block = 256 threads = 256 tiles.
// Phase 1 (DENSE matching — every lane active; the round-4 regression came
//   from lane-sparse matching waves): thread i matches tile t0+i -> LDS.
// Phase 2: block writes its 5632 float4s block-strided (fully coalesced),
//   gathering matched true locs/fluxes. Matched rows always have indicator
//   1.0 (one2one implies match2[k] < tn).
__global__ __launch_bounds__(256) void mvd_fused_dense(
    const float4* __restrict__ el4,   // est_locs  [TT*4] float4
    const float4* __restrict__ tl4,   // true_locs [TT*4] float4
    const float*  __restrict__ tf,    // true_fluxes [TT*64]
    const int*    __restrict__ en_,
    const int*    __restrict__ tn_,
    float4*       __restrict__ out4)  // [TT*22]
{
#pragma clang fp contract(off)
    const int t0 = blockIdx.x * 256;
    const int t  = t0 + threadIdx.x;

    __shared__ int s_rowsrc[256];

    // ---------------- Phase 1: dense per-thread matching ----------------
    {
        const int en = en_[t];
        const int tn = tn_[t];

        float4 ea = el4[t * 4 + 0], eb = el4[t * 4 + 1];
        float4 ec = el4[t * 4 + 2], ed = el4[t * 4 + 3];
        float4 ta = tl4[t * 4 + 0], tb = tl4[t * 4 + 1];
        float4 tc = tl4[t * 4 + 2], td = tl4[t * 4 + 3];

        float mex[8], mey[8], mtx[8], mty[8];
        {
            const float exs[8] = {ea.x, ea.z, eb.x, eb.z, ec.x, ec.z, ed.x, ed.z};
            const float eys[8] = {ea.y, ea.w, eb.y, eb.w, ec.y, ec.w, ed.y, ed.w};
            const float txs[8] = {ta.x, ta.z, tb.x, tb.z, tc.x, tc.z, td.x, td.z};
            const float tys[8] = {ta.y, ta.w, tb.y, tb.w, tc.y, tc.w, td.y, td.w};
#pragma unroll
            for (int i = 0; i < 8; i++) {
                mex[i] = (i < en) ? exs[i] : 100.0f;
                mey[i] = (i < en) ? eys[i] : 100.0f;
                mtx[i] = (i < tn) ? txs[i] : 100.0f;
                mty[i] = (i < tn) ? tys[i] : 100.0f;
            }
        }

        // sqrt REQUIRED: fp32 sqrt rounding can merge values distinct in
        // squared form; numpy argmin tie-breaks to the earlier index on the
        // rounded values. HIP sqrtf (no -ffast-math) is IEEE == np.sqrt.
        // Strict '<' + ascending index == numpy first-occurrence argmin.
        float colmin[8];
        int   m1[8], m2[8];
#pragma unroll
        for (int j = 0; j < 8; j++) { colmin[j] = 1e30f; m1[j] = 0; }
#pragma unroll
        for (int i = 0; i < 8; i++) {
            float rmin = 1e30f;
            int   rj = 0;
#pragma unroll
            for (int j = 0; j < 8; j++) {
                float dx = mex[i] - mtx[j];
                float dy = mey[i] - mty[j];
                float dx2 = dx * dx;
                float dy2 = dy * dy;
                float d = sqrtf(dx2 + dy2);
                if (d < rmin) { rmin = d; rj = j; }
                if (d < colmin[j]) { colmin[j] = d; m1[j] = i; }
            }
            m2[i] = rj;
        }

        int m1p = 0;
#pragma unroll
        for (int j = 0; j < 8; j++) m1p |= m1[j] << (3 * j);

        // one2one + scatter (ascending k, last-wins == numpy fancy assign)
        // rowsrc: 4 bits per output row r: (8|j) if matched from true row j
        int rowsrc = 0;
#pragma unroll
        for (int k = 0; k < 8; k++) {
            int j = m2[k];
            int m1j = (m1p >> (3 * j)) & 7;
            bool o2o = (m1j == k) && (m1[k] < en) && (m2[k] < tn);
            if (o2o) {
                int r = m1[k];
                rowsrc = (rowsrc & ~(0xF << (4 * r))) | ((8 | j) << (4 * r));
            }
        }
        s_rowsrc[threadIdx.x] = rowsrc;
    }
    __syncthreads();

    // ---------------- Phase 2: coalesced block-strided output ----------------
    const float* tl = (const float*)tl4;
    float4* oblk = out4 + (size_t)t0 * 22;

#pragma unroll
    for (int it = 0; it < 22; it++) {
        const int i  = threadIdx.x + it * 256;   // 0..5631, float4 within block
        const int tl_ = i / 22;                  // tile-local (magic-mul)
        const int q  = i - tl_ * 22;
        const int w  = s_rowsrc[tl_];
        const int tt = t0 + tl_;

        float res[4];
#pragma unroll
        for (int u = 0; u < 4; u++) {
            int p = 4 * q + u;                   // 0..87 within tile
            int r = (p * 94) >> 10;              // == p/11 for p in [0,88)
            int c = p - r * 11;
            int v = (w >> (4 * r)) & 15;
            float val = 0.0f;
            if (v & 8) {
                int j = v & 7;
                if (c == 10)      val = 1.0f;
                else if (c < 2)   val = tl[(tt << 4) + (j << 1) + c];
                else              val = tf[(tt << 6) + (j << 3) + (c - 2)];
            }
            res[u] = val;
        }
        oblk[i] = make_float4(res[0], res[1], res[2], res[3]);
    }
}

extern "C" void kernel_launch(void* const* d_in, const int* in_sizes, int n_in,
                              void* d_out, int out_size, void* d_ws, size_t ws_size,
                              hipStream_t stream) {
    const float* est_locs    = (const float*)d_in[0];
    const float* true_locs   = (const float*)d_in[1];
    const float* true_fluxes = (const float*)d_in[2];
    const int*   est_n       = (const int*)d_in[3];
    const int*   true_n      = (const int*)d_in[4];
    float* out = (float*)d_out;

    mvd_fused_dense<<<TT / 256, 256, 0, stream>>>(
        (const float4*)est_locs, (const float4*)true_locs, true_fluxes,
        est_n, true_n, (float4*)out);
}

// Round 6
// 150.846 us; speedup vs baseline: 1.3332x; 1.0032x over previous
//
#include <hip/hip_runtime.h>
#include <math.h>

// Tiles: B*NTH*NTW = 64*56*56
constexpr int TT = 64 * 56 * 56;   // 200704 == 3136 * 64
// M = 8 slots, DF = 8 flux dims, output row = 2 + 8 + 1 = 11 floats
// out per tile = 88 floats = 22 float4.
//
// One block = 64 threads = 64 tiles (ONE wave). 3136 blocks -> 12.25
// blocks/CU: load imbalance 6% vs 31% for the 784-block grid (3.06/CU,
// 16 CUs ran 4 blocks while 240 ran 3 — the round-5 tail).
// Phase 1: dense matching, thread i matches tile t0+i (all 64 lanes busy).
// Phase 2: wave writes its 64*22=1408 float4s coalesced, gathering matched
//   true locs/fluxes. Matched rows always have indicator 1.0 (one2one
//   implies match2[k] < tn).
__global__ __launch_bounds__(64) void mvd_fused_dense64(
    const float4* __restrict__ el4,   // est_locs  [TT*4] float4
    const float4* __restrict__ tl4,   // true_locs [TT*4] float4
    const float*  __restrict__ tf,    // true_fluxes [TT*64]
    const int*    __restrict__ en_,
    const int*    __restrict__ tn_,
    float4*       __restrict__ out4)  // [TT*22]
{
#pragma clang fp contract(off)
    const int t0 = blockIdx.x * 64;
    const int t  = t0 + threadIdx.x;

    __shared__ int s_rowsrc[64];

    // ---------------- Phase 1: dense per-thread matching ----------------
    {
        const int en = en_[t];
        const int tn = tn_[t];

        float4 ea = el4[t * 4 + 0], eb = el4[t * 4 + 1];
        float4 ec = el4[t * 4 + 2], ed = el4[t * 4 + 3];
        float4 ta = tl4[t * 4 + 0], tb = tl4[t * 4 + 1];
        float4 tc = tl4[t * 4 + 2], td = tl4[t * 4 + 3];

        float mex[8], mey[8], mtx[8], mty[8];
        {
            const float exs[8] = {ea.x, ea.z, eb.x, eb.z, ec.x, ec.z, ed.x, ed.z};
            const float eys[8] = {ea.y, ea.w, eb.y, eb.w, ec.y, ec.w, ed.y, ed.w};
            const float txs[8] = {ta.x, ta.z, tb.x, tb.z, tc.x, tc.z, td.x, td.z};
            const float tys[8] = {ta.y, ta.w, tb.y, tb.w, tc.y, tc.w, td.y, td.w};
#pragma unroll
            for (int i = 0; i < 8; i++) {
                mex[i] = (i < en) ? exs[i] : 100.0f;
                mey[i] = (i < en) ? eys[i] : 100.0f;
                mtx[i] = (i < tn) ? txs[i] : 100.0f;
                mty[i] = (i < tn) ? tys[i] : 100.0f;
            }
        }

        // sqrt REQUIRED: fp32 sqrt rounding can merge values distinct in
        // squared form; numpy argmin tie-breaks to the earlier index on the
        // rounded values. HIP sqrtf (no -ffast-math) is IEEE == np.sqrt.
        // Strict '<' + ascending index == numpy first-occurrence argmin.
        float colmin[8];
        int   m1[8], m2[8];
#pragma unroll
        for (int j = 0; j < 8; j++) { colmin[j] = 1e30f; m1[j] = 0; }
#pragma unroll
        for (int i = 0; i < 8; i++) {
            float rmin = 1e30f;
            int   rj = 0;
#pragma unroll
            for (int j = 0; j < 8; j++) {
                float dx = mex[i] - mtx[j];
                float dy = mey[i] - mty[j];
                float dx2 = dx * dx;
                float dy2 = dy * dy;
                float d = sqrtf(dx2 + dy2);
                if (d < rmin) { rmin = d; rj = j; }
                if (d < colmin[j]) { colmin[j] = d; m1[j] = i; }
            }
            m2[i] = rj;
        }

        int m1p = 0;
#pragma unroll
        for (int j = 0; j < 8; j++) m1p |= m1[j] << (3 * j);

        // one2one + scatter (ascending k, last-wins == numpy fancy assign)
        // rowsrc: 4 bits per output row r: (8|j) if matched from true row j
        int rowsrc = 0;
#pragma unroll
        for (int k = 0; k < 8; k++) {
            int j = m2[k];
            int m1j = (m1p >> (3 * j)) & 7;
            bool o2o = (m1j == k) && (m1[k] < en) && (m2[k] < tn);
            if (o2o) {
                int r = m1[k];
                rowsrc = (rowsrc & ~(0xF << (4 * r))) | ((8 | j) << (4 * r));
            }
        }
        s_rowsrc[threadIdx.x] = rowsrc;
    }
    __syncthreads();   // single-wave block: compiles to a cheap waitcnt

    // ---------------- Phase 2: coalesced wave-strided output ----------------
    const float* tl = (const float*)tl4;
    float4* oblk = out4 + (size_t)t0 * 22;

#pragma unroll
    for (int it = 0; it < 22; it++) {
        const int i   = threadIdx.x + it * 64;   // 0..1407, float4 within block
        const int tl_ = i / 22;                  // tile-local (magic-mul)
        const int q   = i - tl_ * 22;
        const int w   = s_rowsrc[tl_];
        const int tt  = t0 + tl_;

        float res[4];
#pragma unroll
        for (int u = 0; u < 4; u++) {
            int p = 4 * q + u;                   // 0..87 within tile
            int r = (p * 94) >> 10;              // == p/11 for p in [0,88)
            int c = p - r * 11;
            int v = (w >> (4 * r)) & 15;
            float val = 0.0f;
            if (v & 8) {
                int j = v & 7;
                if (c == 10)      val = 1.0f;
                else if (c < 2)   val = tl[(tt << 4) + (j << 1) + c];
                else              val = tf[(tt << 6) + (j << 3) + (c - 2)];
            }
            res[u] = val;
        }
        oblk[i] = make_float4(res[0], res[1], res[2], res[3]);
    }
}

extern "C" void kernel_launch(void* const* d_in, const int* in_sizes, int n_in,
                              void* d_out, int out_size, void* d_ws, size_t ws_size,
                              hipStream_t stream) {
    const float* est_locs    = (const float*)d_in[0];
    const float* true_locs   = (const float*)d_in[1];
    const float* true_fluxes = (const float*)d_in[2];
    const int*   est_n       = (const int*)d_in[3];
    const int*   true_n      = (const int*)d_in[4];
    float* out = (float*)d_out;

    mvd_fused_dense64<<<TT / 64, 64, 0, stream>>>(
        (const float4*)est_locs, (const float4*)true_locs, true_fluxes,
        est_n, true_n, (float4*)out);
}

// Round 7
// 149.159 us; speedup vs baseline: 1.3482x; 1.0113x over previous
//
#include <hip/hip_runtime.h>
#include <math.h>

// Tiles: B*NTH*NTW = 64*56*56
constexpr int TT = 64 * 56 * 56;   // 200704 == 3136 * 64
// M = 8 slots, DF = 8 flux dims, output row = 2 + 8 + 1 = 11 floats
// out per tile = 88 floats = 22 float4.
//
// One block = 1 wave = 64 tiles. Round-6 lesson: the limiter was ~176
// divergent global gathers/wave in phase 2 (TA address-processing +
// unhidden latency). Fix: block's true_locs (4KB) + true_fluxes (16KB)
// slices are CONTIGUOUS in global -> stage into LDS with 20 coalesced
// dwordx4 loads, gather from LDS (ds_read_b32; bank image 8j+c' with
// random j and mixed c covers all 32 banks -> ~2-way, free per m136).
// Stores remain fully coalesced dwordx4. rowsrc shared via __shfl.
__global__ __launch_bounds__(64) void mvd_lds_gather(
    const float4* __restrict__ el4,   // est_locs  [TT*4] float4
    const float4* __restrict__ tl4,   // true_locs [TT*4] float4
    const float4* __restrict__ tf4,   // true_fluxes [TT*16] float4
    const int*    __restrict__ en_,
    const int*    __restrict__ tn_,
    float4*       __restrict__ out4)  // [TT*22]
{
#pragma clang fp contract(off)
    const int lane = threadIdx.x;
    const int t0   = blockIdx.x * 64;
    const int t    = t0 + lane;

    // s_mem[0..1023]   = true_locs tiles  (tile*16 + f)
    // s_mem[1024..5119]= true_fluxes tiles (tile*64 + f)
    __shared__ float s_mem[1024 + 4096];   // 20 KB -> 8 blocks/CU by LDS

    // ---- coalesced staging: global slices are contiguous ----
    {
        float4* sm4 = (float4*)s_mem;
#pragma unroll
        for (int k = 0; k < 4; k++)          // true_locs: 4 * 1KB
            sm4[k * 64 + lane] = tl4[(size_t)t0 * 4 + k * 64 + lane];
#pragma unroll
        for (int k = 0; k < 16; k++)         // true_fluxes: 16 * 1KB
            sm4[256 + k * 64 + lane] = tf4[(size_t)t0 * 16 + k * 64 + lane];
    }

    // ---- dense per-thread matching (own tile) while staging lands ----
    int rowsrc = 0;
    {
        const int en = en_[t];
        const int tn = tn_[t];

        float4 ea = el4[t * 4 + 0], eb = el4[t * 4 + 1];
        float4 ec = el4[t * 4 + 2], ed = el4[t * 4 + 3];
        float4 ta = tl4[t * 4 + 0], tb = tl4[t * 4 + 1];
        float4 tc = tl4[t * 4 + 2], td = tl4[t * 4 + 3];

        float mex[8], mey[8], mtx[8], mty[8];
        {
            const float exs[8] = {ea.x, ea.z, eb.x, eb.z, ec.x, ec.z, ed.x, ed.z};
            const float eys[8] = {ea.y, ea.w, eb.y, eb.w, ec.y, ec.w, ed.y, ed.w};
            const float txs[8] = {ta.x, ta.z, tb.x, tb.z, tc.x, tc.z, td.x, td.z};
            const float tys[8] = {ta.y, ta.w, tb.y, tb.w, tc.y, tc.w, td.y, td.w};
#pragma unroll
            for (int i = 0; i < 8; i++) {
                mex[i] = (i < en) ? exs[i] : 100.0f;
                mey[i] = (i < en) ? eys[i] : 100.0f;
                mtx[i] = (i < tn) ? txs[i] : 100.0f;
                mty[i] = (i < tn) ? tys[i] : 100.0f;
            }
        }

        // sqrt REQUIRED: fp32 sqrt rounding can merge values distinct in
        // squared form; numpy argmin tie-breaks to the earlier index on
        // the rounded values. Default HIP sqrtf is IEEE == np.sqrt.
        // Strict '<' + ascending index == numpy first-occurrence argmin.
        float colmin[8];
        int   m1[8], m2[8];
#pragma unroll
        for (int j = 0; j < 8; j++) { colmin[j] = 1e30f; m1[j] = 0; }
#pragma unroll
        for (int i = 0; i < 8; i++) {
            float rmin = 1e30f;
            int   rj = 0;
#pragma unroll
            for (int j = 0; j < 8; j++) {
                float dx = mex[i] - mtx[j];
                float dy = mey[i] - mty[j];
                float dx2 = dx * dx;
                float dy2 = dy * dy;
                float d = sqrtf(dx2 + dy2);
                if (d < rmin) { rmin = d; rj = j; }
                if (d < colmin[j]) { colmin[j] = d; m1[j] = i; }
            }
            m2[i] = rj;
        }

        int m1p = 0;
#pragma unroll
        for (int j = 0; j < 8; j++) m1p |= m1[j] << (3 * j);

        // one2one + scatter (ascending k, last-wins == numpy fancy assign)
        // rowsrc: 4 bits per row r: (8|j) if matched from true row j
#pragma unroll
        for (int k = 0; k < 8; k++) {
            int j = m2[k];
            int m1j = (m1p >> (3 * j)) & 7;
            bool o2o = (m1j == k) && (m1[k] < en) && (m2[k] < tn);
            if (o2o) {
                int r = m1[k];
                rowsrc = (rowsrc & ~(0xF << (4 * r))) | ((8 | j) << (4 * r));
            }
        }
    }
    __syncthreads();   // single wave: waitcnt only, no real barrier cost

    // ---- phase 2: coalesced output, gathers from LDS ----
    float4* oblk = out4 + (size_t)t0 * 22;

#pragma unroll
    for (int it = 0; it < 22; it++) {
        const int i   = lane + it * 64;          // 0..1407 float4 in block
        const int tl_ = (i * 2979) >> 16;        // == i/22 for i < 1408
        const int q   = i - tl_ * 22;
        const int w   = __shfl(rowsrc, tl_);     // tile tl_'s match word

        float res[4];
#pragma unroll
        for (int u = 0; u < 4; u++) {
            int p = 4 * q + u;                   // 0..87 within tile
            int r = (p * 94) >> 10;              // == p/11 for p < 88
            int c = p - r * 11;
            int v = (w >> (4 * r)) & 15;
            bool matched = (v & 8) != 0;
            int  j = v & 7;
            // LDS gather address (0 for lanes that don't need a value)
            int a_tl = tl_ * 16 + 2 * j + c;            // valid when c < 2
            int a_tf = 1024 + tl_ * 64 + 8 * j + (c-2); // valid when 2<=c<10
            int addr = (!matched || c >= 10) ? 0 : (c < 2 ? a_tl : a_tf);
            float val = s_mem[addr];
            res[u] = matched ? (c == 10 ? 1.0f : val) : 0.0f;
        }
        oblk[i] = make_float4(res[0], res[1], res[2], res[3]);
    }
}

extern "C" void kernel_launch(void* const* d_in, const int* in_sizes, int n_in,
                              void* d_out, int out_size, void* d_ws, size_t ws_size,
                              hipStream_t stream) {
    const float* est_locs    = (const float*)d_in[0];
    const float* true_locs   = (const float*)d_in[1];
    const float* true_fluxes = (const float*)d_in[2];
    const int*   est_n       = (const int*)d_in[3];
    const int*   true_n      = (const int*)d_in[4];
    float* out = (float*)d_out;

    mvd_lds_gather<<<TT / 64, 64, 0, stream>>>(
        (const float4*)est_locs, (const float4*)true_locs,
        (const float4*)true_fluxes, est_n, true_n, (float4*)out);
}